// Round 1
// baseline (2186.481 us; speedup 1.0000x reference)
//
#include <hip/hip_runtime.h>
#include <hip/hip_bf16.h>
#include <math.h>

#define B_ 64
#define L_ 57
#define D_ 512
#define H_ 8
#define DK_ 64
#define NC_ 2048

// ---------------- conv1d: y[b][cout][t] = sum_{cin,k} x[b][cin][t*S+k]*w[cout][cin][k] + bias
// Block: 64 t-positions x 64 couts. 256 thr = 64 lanes(t) x 4 groups(16 couts each).
// Input tile staged in LDS (cin-chunked); weights are wave-uniform -> scalar loads.
template<int CIN, int K, int S, int COUT>
__global__ __launch_bounds__(256) void conv1d_k(
    const float* __restrict__ x, const float* __restrict__ w,
    const float* __restrict__ bias, float* __restrict__ y,
    int Tin, int Tout)
{
  constexpr int TT = 64;
  constexpr int SPAN = S * TT + K - S;
  constexpr int CC = (CIN == 105) ? 35 : 32;
  __shared__ float xs[CC * SPAN];
  const int b   = blockIdx.z;
  const int cbk = blockIdx.y;
  const int t0  = blockIdx.x * TT;
  const int tid = threadIdx.x;
  const int lane_t = tid & 63;
  const int g = tid >> 6;
  const int coutBase = __builtin_amdgcn_readfirstlane(cbk * 64 + g * 16);
  const int t = t0 + lane_t;
  float acc[16];
#pragma unroll
  for (int j = 0; j < 16; ++j) acc[j] = 0.f;
  const float* xb = x + (size_t)b * CIN * Tin;
  const int xoff0 = t0 * S;
  for (int c0 = 0; c0 < CIN; c0 += CC) {
    __syncthreads();
    for (int e = tid; e < CC * SPAN; e += 256) {
      int cc = e / SPAN, col = e - cc * SPAN;
      int ti = xoff0 + col;
      float v = 0.f;
      if (ti < Tin) v = xb[(size_t)(c0 + cc) * Tin + ti];
      xs[e] = v;
    }
    __syncthreads();
#pragma unroll 2
    for (int cc = 0; cc < CC; ++cc) {
      const float* wr = w + ((size_t)coutBase * CIN + (c0 + cc)) * K;
#pragma unroll
      for (int kk = 0; kk < K; ++kk) {
        float xv = xs[cc * SPAN + lane_t * S + kk];
#pragma unroll
        for (int j = 0; j < 16; ++j)
          acc[j] += xv * wr[(size_t)j * CIN * K + kk];
      }
    }
  }
  if (t < Tout) {
#pragma unroll
    for (int j = 0; j < 16; ++j) {
      int co = coutBase + j;
      y[((size_t)b * COUT + co) * Tout + t] = acc[j] + bias[co];
    }
  }
}

// ---------------- transpose c6 [B,512,57] -> xT [B,57,512]
__global__ __launch_bounds__(256) void transpose_k(const float* __restrict__ c6,
                                                   float* __restrict__ xT)
{
  const int b = blockIdx.y, dt = blockIdx.x;  // 16 tiles of 32 d
  __shared__ float tile[32 * 58];
  const int tid = threadIdx.x;
  const int d0 = dt * 32;
  for (int e = tid; e < 32 * L_; e += 256) {
    int dd = e / L_, l = e - dd * L_;
    tile[dd * 58 + l] = c6[((size_t)b * D_ + d0 + dd) * L_ + l];
  }
  __syncthreads();
  for (int e = tid; e < L_ * 32; e += 256) {
    int l = e >> 5, dd = e & 31;
    xT[((size_t)b * L_ + l) * D_ + d0 + dd] = tile[dd * 58 + l];
  }
}

// ---------------- fused QKV projection: out[b,h,l,kd] for q,k,v
// grid.x = 24 : ot(6 o-tiles of 256 over [q|k|v] x 512) * lt(4 l-tiles of 16) ; grid.y = b
__global__ __launch_bounds__(256) void qkv3_k(
    const float* __restrict__ xT, const float* __restrict__ wq,
    const float* __restrict__ wk, const float* __restrict__ wv,
    float* __restrict__ q, float* __restrict__ k, float* __restrict__ v)
{
  const int b = blockIdx.y;
  const int ot = blockIdx.x >> 2;
  const int lt = blockIdx.x & 3;
  const int l0 = lt * 16;
  __shared__ __align__(16) float cs[16 * D_];
  const int tid = threadIdx.x;
  for (int e = tid; e < 16 * D_; e += 256) {
    int l = l0 + (e >> 9);
    cs[e] = (l < L_) ? xT[((size_t)b * L_ + l) * D_ + (e & 511)] : 0.f;
  }
  __syncthreads();
  const int o3 = ot * 256 + tid;
  const int set = o3 >> 9;            // uniform per block
  const int oo = o3 & 511;
  const int h = oo >> 6, kd = oo & 63;
  const float* W = (set == 0 ? wq : (set == 1 ? wk : wv));
  const float* wp = W + (size_t)h * D_ * DK_ + kd;
  float acc[16];
#pragma unroll
  for (int j = 0; j < 16; ++j) acc[j] = 0.f;
  for (int d = 0; d < D_; d += 4) {
    float w0 = wp[(size_t)d * DK_];
    float w1 = wp[(size_t)(d + 1) * DK_];
    float w2 = wp[(size_t)(d + 2) * DK_];
    float w3 = wp[(size_t)(d + 3) * DK_];
#pragma unroll
    for (int j = 0; j < 16; ++j) {
      const float4 c4 = *reinterpret_cast<const float4*>(&cs[j * D_ + d]);
      acc[j] += c4.x * w0 + c4.y * w1 + c4.z * w2 + c4.w * w3;
    }
  }
  float* OUT = (set == 0 ? q : (set == 1 ? k : v));
#pragma unroll
  for (int j = 0; j < 16; ++j) {
    int l = l0 + j;
    if (l < L_) OUT[(((size_t)b * H_ + h) * L_ + l) * DK_ + kd] = acc[j];
  }
}

// ---------------- attention per (b,h); writes concat layout cat[b][l][h*64+kd]
__global__ __launch_bounds__(256) void attn_k(
    const float* __restrict__ q, const float* __restrict__ k, const float* __restrict__ v,
    float* __restrict__ cat)
{
  const int bh = blockIdx.x;
  const int b = bh >> 3, h = bh & 7;
  __shared__ float qs[L_ * DK_];
  __shared__ float ks[L_ * 65];      // padded: kills 32-way bank conflict
  __shared__ float vs[L_ * DK_];
  __shared__ float ps[L_ * DK_];
  const int tid = threadIdx.x;
  const float* qb = q + (size_t)bh * L_ * DK_;
  const float* kb = k + (size_t)bh * L_ * DK_;
  const float* vb = v + (size_t)bh * L_ * DK_;
  for (int e = tid; e < L_ * DK_; e += 256) {
    qs[e] = qb[e];
    vs[e] = vb[e];
    int m = e >> 6, d = e & 63;
    ks[m * 65 + d] = kb[e];
  }
  __syncthreads();
  for (int e = tid; e < L_ * L_; e += 256) {
    int l = e / L_, m = e - (e / L_) * L_;
    float s = 0.f;
#pragma unroll
    for (int d = 0; d < DK_; ++d) s += qs[l * DK_ + d] * ks[m * 65 + d];
    ps[l * DK_ + m] = s * 0.125f;
  }
  __syncthreads();
  if (tid < L_) {
    float mx = -1e30f;
    for (int m = 0; m < L_; ++m) mx = fmaxf(mx, ps[tid * DK_ + m]);
    float sum = 0.f;
    for (int m = 0; m < L_; ++m) { float e2 = __expf(ps[tid * DK_ + m] - mx); ps[tid * DK_ + m] = e2; sum += e2; }
    float inv = 1.f / sum;
    for (int m = 0; m < L_; ++m) ps[tid * DK_ + m] *= inv;
  }
  __syncthreads();
  for (int e = tid; e < L_ * DK_; e += 256) {
    int l = e >> 6, kd = e & 63;
    float s = 0.f;
    for (int m = 0; m < L_; ++m) s += ps[l * DK_ + m] * vs[m * DK_ + kd];
    cat[((size_t)b * L_ + l) * D_ + h * DK_ + kd] = s;
  }
}

// ---------------- output projection: y[b,l,o] = cat[b,l,:] @ wo + bo
__global__ __launch_bounds__(256) void outproj_k(
    const float* __restrict__ cat, const float* __restrict__ wo,
    const float* __restrict__ bo, float* __restrict__ y)
{
  const int b = blockIdx.y, lt = blockIdx.x;
  const int l0 = lt * 16;
  __shared__ __align__(16) float cs[16 * D_];
  const int tid = threadIdx.x;
  for (int e = tid; e < 16 * D_; e += 256) {
    int l = l0 + (e >> 9);
    cs[e] = (l < L_) ? cat[((size_t)b * L_ + l) * D_ + (e & 511)] : 0.f;
  }
  __syncthreads();
  float acc0[16], acc1[16];
#pragma unroll
  for (int j = 0; j < 16; ++j) { acc0[j] = 0.f; acc1[j] = 0.f; }
  for (int d = 0; d < D_; d += 4) {
    float w00 = wo[(size_t)d * D_ + tid];
    float w01 = wo[(size_t)(d + 1) * D_ + tid];
    float w02 = wo[(size_t)(d + 2) * D_ + tid];
    float w03 = wo[(size_t)(d + 3) * D_ + tid];
    float w10 = wo[(size_t)d * D_ + tid + 256];
    float w11 = wo[(size_t)(d + 1) * D_ + tid + 256];
    float w12 = wo[(size_t)(d + 2) * D_ + tid + 256];
    float w13 = wo[(size_t)(d + 3) * D_ + tid + 256];
#pragma unroll
    for (int j = 0; j < 16; ++j) {
      const float4 c4 = *reinterpret_cast<const float4*>(&cs[j * D_ + d]);
      acc0[j] += c4.x * w00 + c4.y * w01 + c4.z * w02 + c4.w * w03;
      acc1[j] += c4.x * w10 + c4.y * w11 + c4.z * w12 + c4.w * w13;
    }
  }
#pragma unroll
  for (int j = 0; j < 16; ++j) {
    int l = l0 + j;
    if (l < L_) {
      y[((size_t)b * L_ + l) * D_ + tid] = acc0[j] + bo[tid];
      y[((size_t)b * L_ + l) * D_ + tid + 256] = acc1[j] + bo[tid + 256];
    }
  }
}

// ---------------- codebook prep: transpose to [d][n] + norms
__global__ __launch_bounds__(64) void cbprep_k(const float* __restrict__ cb,
                                               float* __restrict__ cbT,
                                               float* __restrict__ cnorm)
{
  const int n = blockIdx.x, t = threadIdx.x;
  float s = 0.f;
  for (int d = t; d < D_; d += 64) {
    float vv = cb[(size_t)n * D_ + d];
    cbT[(size_t)d * NC_ + n] = vv;
    s += vv * vv;
  }
#pragma unroll
  for (int off = 32; off >= 1; off >>= 1) s += __shfl_xor(s, off);
  if (t == 0) cnorm[n] = s;
}

// ---------------- VQ partial argmin: block = (b, tile of 256 codes)
__global__ __launch_bounds__(256) void vqpart_k(
    const float* __restrict__ y, const float* __restrict__ cbT,
    const float* __restrict__ cnorm, float* __restrict__ pmin, int* __restrict__ pidx)
{
  const int b = blockIdx.y, nt = blockIdx.x;
  const int tid = threadIdx.x;
  const int n = nt * 256 + tid;
  float dot[L_];
#pragma unroll
  for (int l = 0; l < L_; ++l) dot[l] = 0.f;
  __shared__ __align__(16) float as[L_ * 32];
  for (int d0 = 0; d0 < D_; d0 += 32) {
    __syncthreads();
    for (int e = tid; e < L_ * 32; e += 256) {
      int l = e >> 5, dd = e & 31;
      as[e] = y[((size_t)b * L_ + l) * D_ + d0 + dd];
    }
    __syncthreads();
    float cr[32];
#pragma unroll
    for (int dd = 0; dd < 32; ++dd) cr[dd] = cbT[(size_t)(d0 + dd) * NC_ + n];
#pragma unroll
    for (int l = 0; l < L_; ++l) {
#pragma unroll
      for (int dd = 0; dd < 32; dd += 4) {
        const float4 a4 = *reinterpret_cast<const float4*>(&as[l * 32 + dd]);
        dot[l] += a4.x * cr[dd] + a4.y * cr[dd + 1] + a4.z * cr[dd + 2] + a4.w * cr[dd + 3];
      }
    }
  }
  const float base = cnorm[n];
  const int lane = tid & 63, wvi = tid >> 6;
  __shared__ float wmin[4][L_];
  __shared__ int   widx[4][L_];
#pragma unroll
  for (int l = 0; l < L_; ++l) {
    float vb = base - 2.f * dot[l];
    int ib = n;
#pragma unroll
    for (int off = 32; off >= 1; off >>= 1) {
      float vo = __shfl_xor(vb, off);
      int io = __shfl_xor(ib, off);
      if (vo < vb || (vo == vb && io < ib)) { vb = vo; ib = io; }
    }
    if (lane == 0) { wmin[wvi][l] = vb; widx[wvi][l] = ib; }
  }
  __syncthreads();
  if (tid < L_) {
    float vb = wmin[0][tid]; int ib = widx[0][tid];
#pragma unroll
    for (int w2 = 1; w2 < 4; ++w2) {
      float vo = wmin[w2][tid]; int io = widx[w2][tid];
      if (vo < vb || (vo == vb && io < ib)) { vb = vo; ib = io; }
    }
    pmin[((size_t)b * L_ + tid) * 8 + nt] = vb;
    pidx[((size_t)b * L_ + tid) * 8 + nt] = ib;
  }
}

// ---------------- VQ final: pick global argmin, emit z_q + index + loss partial
__global__ __launch_bounds__(64) void vqfin_k(
    const float* __restrict__ y, const float* __restrict__ cbook,
    const float* __restrict__ pmin, const int* __restrict__ pidx,
    float* __restrict__ zq, float* __restrict__ oidx, float* __restrict__ lpart)
{
  const int bl = blockIdx.x;
  const int tid = threadIdx.x;
  __shared__ int sidx;
  if (tid == 0) {
    float vb = pmin[(size_t)bl * 8];
    int ib = pidx[(size_t)bl * 8];
    for (int ntv = 1; ntv < 8; ++ntv) {
      float vo = pmin[(size_t)bl * 8 + ntv];
      int io = pidx[(size_t)bl * 8 + ntv];
      if (vo < vb || (vo == vb && io < ib)) { vb = vo; ib = io; }
    }
    sidx = ib;
  }
  __syncthreads();
  const int idx = sidx;
  const float* crow = cbook + (size_t)idx * D_;
  const float* yrow = y + (size_t)bl * D_;
  float s = 0.f;
  for (int d = tid; d < D_; d += 64) {
    float c = crow[d];
    float df = c - yrow[d];
    zq[(size_t)bl * D_ + d] = c;
    s += df * df;
  }
#pragma unroll
  for (int off = 32; off >= 1; off >>= 1) s += __shfl_xor(s, off);
  if (tid == 0) { lpart[bl] = s; oidx[bl] = (float)idx; }
}

// ---------------- loss reduce (deterministic fixed-order)
__global__ __launch_bounds__(256) void loss_k(const float* __restrict__ lpart,
                                              float* __restrict__ outLoss)
{
  const int tid = threadIdx.x;
  float s = 0.f;
  for (int i = tid; i < B_ * L_; i += 256) s += lpart[i];
  __shared__ float red[256];
  red[tid] = s;
  __syncthreads();
  for (int off = 128; off >= 1; off >>= 1) {
    if (tid < off) red[tid] += red[tid + off];
    __syncthreads();
  }
  if (tid == 0) outLoss[0] = red[0] * ((1.f + 0.2f) / (float)((size_t)B_ * L_ * D_));
}

extern "C" void kernel_launch(void* const* d_in, const int* in_sizes, int n_in,
                              void* d_out, int out_size, void* d_ws, size_t ws_size,
                              hipStream_t stream)
{
  const float* x  = (const float*)d_in[0];
  const float* w1 = (const float*)d_in[1];  const float* b1 = (const float*)d_in[2];
  const float* w2 = (const float*)d_in[3];  const float* b2 = (const float*)d_in[4];
  const float* w3 = (const float*)d_in[5];  const float* b3 = (const float*)d_in[6];
  const float* w4 = (const float*)d_in[7];  const float* b4 = (const float*)d_in[8];
  const float* w5 = (const float*)d_in[9];  const float* b5 = (const float*)d_in[10];
  const float* w6 = (const float*)d_in[11]; const float* b6 = (const float*)d_in[12];
  const float* wq = (const float*)d_in[13];
  const float* wk = (const float*)d_in[14];
  const float* wv = (const float*)d_in[15];
  const float* wo = (const float*)d_in[16];
  const float* bo = (const float*)d_in[17];
  const float* cbook = (const float*)d_in[18];

  float* ws = (float*)d_ws;
  // Workspace layout (floats). Two 30MB conv ping-pong buffers; everything
  // after the conv stack reuses dead regions inside bufB. Total ~50 MB.
  float* bufA  = ws;                 // max 7,500,000 floats
  float* bufB  = ws + 7500000;       // max 7,500,000 floats
  float* cat   = bufB;               // 1,867,776 (c6 dead after transpose)
  float* yattn = ws + 9400000;       // 1,867,776
  float* cbT   = ws + 11300000;      // 1,048,576
  float* cnorm = ws + 12400000;      // 2048
  float* pminb = ws + 12410000;      // 29184
  int*   pidxb = (int*)(ws + 12440000); // 29184
  float* lpart = ws + 12470000;      // 3648

  float* zq      = (float*)d_out;
  float* outLoss = zq + (size_t)B_ * L_ * D_;
  float* outIdx  = outLoss + 1;

  // conv stack: x -> c1(A) -> c2(B) -> c3(A) -> c4(B) -> c5(A) -> c6(B)
  conv1d_k<105,10,3, 64><<<dim3(29,1,64),256,0,stream>>>(x,    w1,b1, bufA, 5500,1831);
  conv1d_k< 64, 3,2,128><<<dim3(15,2,64),256,0,stream>>>(bufA, w2,b2, bufB, 1831, 915);
  conv1d_k<128, 3,2,256><<<dim3( 8,4,64),256,0,stream>>>(bufB, w3,b3, bufA,  915, 457);
  conv1d_k<256, 3,2,512><<<dim3( 4,8,64),256,0,stream>>>(bufA, w4,b4, bufB,  457, 228);
  conv1d_k<512, 2,2,512><<<dim3( 2,8,64),256,0,stream>>>(bufB, w5,b5, bufA,  228, 114);
  conv1d_k<512, 2,2,512><<<dim3( 1,8,64),256,0,stream>>>(bufA, w6,b6, bufB,  114,  57);

  // attention inputs live in bufA (c5 dead): q,k,v then xT
  float* qb = bufA;
  float* kb = bufA + 1867776;
  float* vb = bufA + 3735552;
  float* xT = bufA + 5603328;

  transpose_k<<<dim3(16, B_), 256, 0, stream>>>(bufB, xT);
  qkv3_k<<<dim3(24, B_), 256, 0, stream>>>(xT, wq, wk, wv, qb, kb, vb);
  cbprep_k<<<NC_, 64, 0, stream>>>(cbook, cbT, cnorm);   // after convs: aliases dead conv scratch
  attn_k<<<B_ * H_, 256, 0, stream>>>(qb, kb, vb, cat);
  outproj_k<<<dim3(4, B_), 256, 0, stream>>>(cat, wo, bo, yattn);

  vqpart_k<<<dim3(8, B_), 256, 0, stream>>>(yattn, cbT, cnorm, pminb, pidxb);
  vqfin_k<<<B_ * L_, 64, 0, stream>>>(yattn, cbook, pminb, pidxb, zq, outIdx, lpart);
  loss_k<<<1, 256, 0, stream>>>(lpart, outLoss);
}

// Round 3
// 2105.661 us; speedup vs baseline: 1.0384x; 1.0384x over previous
//
#include <hip/hip_runtime.h>
#include <hip/hip_bf16.h>
#include <math.h>

#define B_ 64
#define HB_ 32
#define L_ 57
#define D_ 512
#define H_ 8
#define DK_ 64
#define NC_ 2048

// ---------------- weight transpose: w[cout][cin][k] -> wT[cin*K + k][cout]
__global__ __launch_bounds__(256) void wtrans_k(const float* __restrict__ w,
                                                float* __restrict__ wT,
                                                int CINK, int COUT)
{
  int idx = blockIdx.x * 256 + threadIdx.x;
  if (idx >= CINK * COUT) return;
  int r = idx / COUT, c = idx - r * COUT;
  wT[idx] = w[(size_t)c * CINK + r];
}

// ---------------- conv1d over a 32-batch half:
// y[b][cout][t] = sum_{cin,k} x[b][cin][t*S+k]*wT[cin*K+k][cout] + bias
// Block: 64 t x 64 couts; 256 thr = 64 lanes(t) x 4 waves(16 couts each).
// x tile staged in LDS; weight rows are wave-uniform contiguous 16 floats ->
// wide scalar loads batched ahead of each 16-FMA block.
template<int CIN, int K, int S, int COUT, int CC>
__global__ __launch_bounds__(256) void conv1d_k(
    const float* __restrict__ x, const float* __restrict__ wT,
    const float* __restrict__ bias, float* __restrict__ y,
    int Tin, int Tout)
{
  constexpr int TT = 64;
  constexpr int SPAN = S * TT + K - S;   // <= 256 for all configs
  __shared__ float xs[CC * SPAN];
  const int b   = blockIdx.z;
  const int cbk = blockIdx.y;
  const int t0  = blockIdx.x * TT;
  const int tid = threadIdx.x;
  const int lane_t = tid & 63;
  const int g = tid >> 6;
  const int coutBase = __builtin_amdgcn_readfirstlane(cbk * 64 + g * 16);
  const int t = t0 + lane_t;
  float acc[16];
#pragma unroll
  for (int j = 0; j < 16; ++j) acc[j] = 0.f;
  const float* xb = x + (size_t)b * CIN * Tin;
  const int col0 = t0 * S;

  for (int c0 = 0; c0 < CIN; c0 += CC) {
    __syncthreads();
    for (int e = tid; e < CC * SPAN; e += 256) {
      int cc = e / SPAN, col = e - cc * SPAN;   // SPAN constexpr -> cheap
      int ti = col0 + col;
      xs[e] = (ti < Tin) ? xb[(size_t)(c0 + cc) * Tin + ti] : 0.f;
    }
    __syncthreads();

    const float* wchunk = wT + ((size_t)c0 * K) * COUT + coutBase;
    for (int cc = 0; cc < CC; ++cc) {
#pragma unroll
      for (int kk = 0; kk < K; ++kk) {
        const float* wrow = wchunk + (size_t)(cc * K + kk) * COUT;
        float wv[16];
#pragma unroll
        for (int j = 0; j < 16; ++j) wv[j] = wrow[j];
        float xv = xs[cc * SPAN + lane_t * S + kk];
#pragma unroll
        for (int j = 0; j < 16; ++j) acc[j] += xv * wv[j];
      }
    }
  }
  if (t < Tout) {
#pragma unroll
    for (int j = 0; j < 16; ++j) {
      int co = coutBase + j;
      y[((size_t)b * COUT + co) * Tout + t] = acc[j] + bias[co];
    }
  }
}

// ---------------- transpose c6 [B,512,57] -> xT [B,57,512]
__global__ __launch_bounds__(256) void transpose_k(const float* __restrict__ c6,
                                                   float* __restrict__ xT)
{
  const int b = blockIdx.y, dt = blockIdx.x;  // 16 tiles of 32 d
  __shared__ float tile[32 * 58];
  const int tid = threadIdx.x;
  const int d0 = dt * 32;
  for (int e = tid; e < 32 * L_; e += 256) {
    int dd = e / L_, l = e - dd * L_;
    tile[dd * 58 + l] = c6[((size_t)b * D_ + d0 + dd) * L_ + l];
  }
  __syncthreads();
  for (int e = tid; e < L_ * 32; e += 256) {
    int l = e >> 5, dd = e & 31;
    xT[((size_t)b * L_ + l) * D_ + d0 + dd] = tile[dd * 58 + l];
  }
}

// ---------------- fused QKV projection: out[b,h,l,kd] for q,k,v
__global__ __launch_bounds__(256) void qkv3_k(
    const float* __restrict__ xT, const float* __restrict__ wq,
    const float* __restrict__ wk, const float* __restrict__ wv,
    float* __restrict__ q, float* __restrict__ k, float* __restrict__ v)
{
  const int b = blockIdx.y;
  const int ot = blockIdx.x >> 2;
  const int lt = blockIdx.x & 3;
  const int l0 = lt * 16;
  __shared__ __align__(16) float cs[16 * D_];
  const int tid = threadIdx.x;
  for (int e = tid; e < 16 * D_; e += 256) {
    int l = l0 + (e >> 9);
    cs[e] = (l < L_) ? xT[((size_t)b * L_ + l) * D_ + (e & 511)] : 0.f;
  }
  __syncthreads();
  const int o3 = ot * 256 + tid;
  const int set = o3 >> 9;            // uniform per block
  const int oo = o3 & 511;
  const int h = oo >> 6, kd = oo & 63;
  const float* W = (set == 0 ? wq : (set == 1 ? wk : wv));
  const float* wp = W + (size_t)h * D_ * DK_ + kd;
  float acc[16];
#pragma unroll
  for (int j = 0; j < 16; ++j) acc[j] = 0.f;
  for (int d = 0; d < D_; d += 4) {
    float w0 = wp[(size_t)d * DK_];
    float w1 = wp[(size_t)(d + 1) * DK_];
    float w2 = wp[(size_t)(d + 2) * DK_];
    float w3 = wp[(size_t)(d + 3) * DK_];
#pragma unroll
    for (int j = 0; j < 16; ++j) {
      const float4 c4 = *reinterpret_cast<const float4*>(&cs[j * D_ + d]);
      acc[j] += c4.x * w0 + c4.y * w1 + c4.z * w2 + c4.w * w3;
    }
  }
  float* OUT = (set == 0 ? q : (set == 1 ? k : v));
#pragma unroll
  for (int j = 0; j < 16; ++j) {
    int l = l0 + j;
    if (l < L_) OUT[(((size_t)b * H_ + h) * L_ + l) * DK_ + kd] = acc[j];
  }
}

// ---------------- attention per (b,h); writes concat layout cat[b][l][h*64+kd]
__global__ __launch_bounds__(256) void attn_k(
    const float* __restrict__ q, const float* __restrict__ k, const float* __restrict__ v,
    float* __restrict__ cat)
{
  const int bh = blockIdx.x;
  const int b = bh >> 3, h = bh & 7;
  __shared__ float qs[L_ * DK_];
  __shared__ float ks[L_ * 65];      // padded: kills 32-way bank conflict
  __shared__ float vs[L_ * DK_];
  __shared__ float ps[L_ * DK_];
  const int tid = threadIdx.x;
  const float* qb = q + (size_t)bh * L_ * DK_;
  const float* kb = k + (size_t)bh * L_ * DK_;
  const float* vb = v + (size_t)bh * L_ * DK_;
  for (int e = tid; e < L_ * DK_; e += 256) {
    qs[e] = qb[e];
    vs[e] = vb[e];
    int m = e >> 6, d = e & 63;
    ks[m * 65 + d] = kb[e];
  }
  __syncthreads();
  for (int e = tid; e < L_ * L_; e += 256) {
    int l = e / L_, m = e - (e / L_) * L_;
    float s = 0.f;
#pragma unroll
    for (int d = 0; d < DK_; ++d) s += qs[l * DK_ + d] * ks[m * 65 + d];
    ps[l * DK_ + m] = s * 0.125f;
  }
  __syncthreads();
  if (tid < L_) {
    float mx = -1e30f;
    for (int m = 0; m < L_; ++m) mx = fmaxf(mx, ps[tid * DK_ + m]);
    float sum = 0.f;
    for (int m = 0; m < L_; ++m) { float e2 = __expf(ps[tid * DK_ + m] - mx); ps[tid * DK_ + m] = e2; sum += e2; }
    float inv = 1.f / sum;
    for (int m = 0; m < L_; ++m) ps[tid * DK_ + m] *= inv;
  }
  __syncthreads();
  for (int e = tid; e < L_ * DK_; e += 256) {
    int l = e >> 6, kd = e & 63;
    float s = 0.f;
    for (int m = 0; m < L_; ++m) s += ps[l * DK_ + m] * vs[m * DK_ + kd];
    cat[((size_t)b * L_ + l) * D_ + h * DK_ + kd] = s;
  }
}

// ---------------- output projection: y[b,l,o] = cat[b,l,:] @ wo + bo
__global__ __launch_bounds__(256) void outproj_k(
    const float* __restrict__ cat, const float* __restrict__ wo,
    const float* __restrict__ bo, float* __restrict__ y)
{
  const int b = blockIdx.y, lt = blockIdx.x;
  const int l0 = lt * 16;
  __shared__ __align__(16) float cs[16 * D_];
  const int tid = threadIdx.x;
  for (int e = tid; e < 16 * D_; e += 256) {
    int l = l0 + (e >> 9);
    cs[e] = (l < L_) ? cat[((size_t)b * L_ + l) * D_ + (e & 511)] : 0.f;
  }
  __syncthreads();
  float acc0[16], acc1[16];
#pragma unroll
  for (int j = 0; j < 16; ++j) { acc0[j] = 0.f; acc1[j] = 0.f; }
  for (int d = 0; d < D_; d += 4) {
    float w00 = wo[(size_t)d * D_ + tid];
    float w01 = wo[(size_t)(d + 1) * D_ + tid];
    float w02 = wo[(size_t)(d + 2) * D_ + tid];
    float w03 = wo[(size_t)(d + 3) * D_ + tid];
    float w10 = wo[(size_t)d * D_ + tid + 256];
    float w11 = wo[(size_t)(d + 1) * D_ + tid + 256];
    float w12 = wo[(size_t)(d + 2) * D_ + tid + 256];
    float w13 = wo[(size_t)(d + 3) * D_ + tid + 256];
#pragma unroll
    for (int j = 0; j < 16; ++j) {
      const float4 c4 = *reinterpret_cast<const float4*>(&cs[j * D_ + d]);
      acc0[j] += c4.x * w00 + c4.y * w01 + c4.z * w02 + c4.w * w03;
      acc1[j] += c4.x * w10 + c4.y * w11 + c4.z * w12 + c4.w * w13;
    }
  }
#pragma unroll
  for (int j = 0; j < 16; ++j) {
    int l = l0 + j;
    if (l < L_) {
      y[((size_t)b * L_ + l) * D_ + tid] = acc0[j] + bo[tid];
      y[((size_t)b * L_ + l) * D_ + tid + 256] = acc1[j] + bo[tid + 256];
    }
  }
}

// ---------------- codebook prep: transpose to [d][n] + norms
__global__ __launch_bounds__(64) void cbprep_k(const float* __restrict__ cb,
                                               float* __restrict__ cbT,
                                               float* __restrict__ cnorm)
{
  const int n = blockIdx.x, t = threadIdx.x;
  float s = 0.f;
  for (int d = t; d < D_; d += 64) {
    float vv = cb[(size_t)n * D_ + d];
    cbT[(size_t)d * NC_ + n] = vv;
    s += vv * vv;
  }
#pragma unroll
  for (int off = 32; off >= 1; off >>= 1) s += __shfl_xor(s, off);
  if (t == 0) cnorm[n] = s;
}

// ---------------- VQ partial argmin: block = (b, tile of 256 codes)
__global__ __launch_bounds__(256) void vqpart_k(
    const float* __restrict__ y, const float* __restrict__ cbT,
    const float* __restrict__ cnorm, float* __restrict__ pmin, int* __restrict__ pidx)
{
  const int b = blockIdx.y, nt = blockIdx.x;
  const int tid = threadIdx.x;
  const int n = nt * 256 + tid;
  float dot[L_];
#pragma unroll
  for (int l = 0; l < L_; ++l) dot[l] = 0.f;
  __shared__ __align__(16) float as[L_ * 32];
  for (int d0 = 0; d0 < D_; d0 += 32) {
    __syncthreads();
    for (int e = tid; e < L_ * 32; e += 256) {
      int l = e >> 5, dd = e & 31;
      as[e] = y[((size_t)b * L_ + l) * D_ + d0 + dd];
    }
    __syncthreads();
    float cr[32];
#pragma unroll
    for (int dd = 0; dd < 32; ++dd) cr[dd] = cbT[(size_t)(d0 + dd) * NC_ + n];
#pragma unroll
    for (int l = 0; l < L_; ++l) {
#pragma unroll
      for (int dd = 0; dd < 32; dd += 4) {
        const float4 a4 = *reinterpret_cast<const float4*>(&as[l * 32 + dd]);
        dot[l] += a4.x * cr[dd] + a4.y * cr[dd + 1] + a4.z * cr[dd + 2] + a4.w * cr[dd + 3];
      }
    }
  }
  const float base = cnorm[n];
  const int lane = tid & 63, wvi = tid >> 6;
  __shared__ float wmin[4][L_];
  __shared__ int   widx[4][L_];
#pragma unroll
  for (int l = 0; l < L_; ++l) {
    float vb = base - 2.f * dot[l];
    int ib = n;
#pragma unroll
    for (int off = 32; off >= 1; off >>= 1) {
      float vo = __shfl_xor(vb, off);
      int io = __shfl_xor(ib, off);
      if (vo < vb || (vo == vb && io < ib)) { vb = vo; ib = io; }
    }
    if (lane == 0) { wmin[wvi][l] = vb; widx[wvi][l] = ib; }
  }
  __syncthreads();
  if (tid < L_) {
    float vb = wmin[0][tid]; int ib = widx[0][tid];
#pragma unroll
    for (int w2 = 1; w2 < 4; ++w2) {
      float vo = wmin[w2][tid]; int io = widx[w2][tid];
      if (vo < vb || (vo == vb && io < ib)) { vb = vo; ib = io; }
    }
    pmin[((size_t)b * L_ + tid) * 8 + nt] = vb;
    pidx[((size_t)b * L_ + tid) * 8 + nt] = ib;
  }
}

// ---------------- VQ final: pick global argmin, emit z_q + index + loss partial
__global__ __launch_bounds__(64) void vqfin_k(
    const float* __restrict__ y, const float* __restrict__ cbook,
    const float* __restrict__ pmin, const int* __restrict__ pidx,
    float* __restrict__ zq, float* __restrict__ oidx, float* __restrict__ lpart)
{
  const int bl = blockIdx.x;
  const int tid = threadIdx.x;
  __shared__ int sidx;
  if (tid == 0) {
    float vb = pmin[(size_t)bl * 8];
    int ib = pidx[(size_t)bl * 8];
    for (int ntv = 1; ntv < 8; ++ntv) {
      float vo = pmin[(size_t)bl * 8 + ntv];
      int io = pidx[(size_t)bl * 8 + ntv];
      if (vo < vb || (vo == vb && io < ib)) { vb = vo; ib = io; }
    }
    sidx = ib;
  }
  __syncthreads();
  const int idx = sidx;
  const float* crow = cbook + (size_t)idx * D_;
  const float* yrow = y + (size_t)bl * D_;
  float s = 0.f;
  for (int d = tid; d < D_; d += 64) {
    float c = crow[d];
    float df = c - yrow[d];
    zq[(size_t)bl * D_ + d] = c;
    s += df * df;
  }
#pragma unroll
  for (int off = 32; off >= 1; off >>= 1) s += __shfl_xor(s, off);
  if (tid == 0) { lpart[bl] = s; oidx[bl] = (float)idx; }
}

// ---------------- loss reduce (deterministic fixed-order)
__global__ __launch_bounds__(256) void loss_k(const float* __restrict__ lpart,
                                              float* __restrict__ outLoss)
{
  const int tid = threadIdx.x;
  float s = 0.f;
  for (int i = tid; i < B_ * L_; i += 256) s += lpart[i];
  __shared__ float red[256];
  red[tid] = s;
  __syncthreads();
  for (int off = 128; off >= 1; off >>= 1) {
    if (tid < off) red[tid] += red[tid + off];
    __syncthreads();
  }
  if (tid == 0) outLoss[0] = red[0] * ((1.f + 0.2f) / (float)((size_t)B_ * L_ * D_));
}

extern "C" void kernel_launch(void* const* d_in, const int* in_sizes, int n_in,
                              void* d_out, int out_size, void* d_ws, size_t ws_size,
                              hipStream_t stream)
{
  const float* x  = (const float*)d_in[0];
  const float* w1 = (const float*)d_in[1];  const float* b1 = (const float*)d_in[2];
  const float* w2 = (const float*)d_in[3];  const float* b2 = (const float*)d_in[4];
  const float* w3 = (const float*)d_in[5];  const float* b3 = (const float*)d_in[6];
  const float* w4 = (const float*)d_in[7];  const float* b4 = (const float*)d_in[8];
  const float* w5 = (const float*)d_in[9];  const float* b5 = (const float*)d_in[10];
  const float* w6 = (const float*)d_in[11]; const float* b6 = (const float*)d_in[12];
  const float* wq = (const float*)d_in[13];
  const float* wk = (const float*)d_in[14];
  const float* wv = (const float*)d_in[15];
  const float* wo = (const float*)d_in[16];
  const float* bo = (const float*)d_in[17];
  const float* cbook = (const float*)d_in[18];

  float* ws = (float*)d_ws;
  // ---- Workspace layout (floats), peak 12,319,296 (~49.3MB) ----
  // Conv phase:  wT[0..1,631,872) | bufA[1,632,000..5,382,016) |
  //              bufB[5,382,016..9,132,032) | c6[9,132,032..10,999,808)
  // Post-conv reuses dead conv regions (stream order serializes).
  float* wT1 = ws;                  // 67,200
  float* wT2 = ws + 67200;          // 24,576
  float* wT3 = ws + 91776;          // 98,304
  float* wT4 = ws + 190080;         // 393,216
  float* wT5 = ws + 583296;         // 524,288
  float* wT6 = ws + 1107584;        // 524,288 -> ends 1,631,872
  float* bufA = ws + 1632000;       // 3,750,016 (max half-batch 3,749,888)
  float* bufB = ws + 5382016;       // 3,750,016
  float* c6   = ws + 9132032;       // 1,867,776 (full batch)
  // post-conv:
  float* qb    = ws;                // 1,867,776 (wT dead)
  float* kb    = ws + 1867776;      // 1,867,776 (bufA dead)
  float* vb    = ws + 3735552;      // 1,867,776
  float* xT    = ws + 5603328;      // 1,867,776 (bufB dead after conv5)
  float* cat   = ws + 7471104;      // 1,867,776 (c6 head dead after transpose)
  float* yattn = ws + 9338880;      // 1,867,776 (c6 dead)
  float* cbT   = ws + 11206656;     // 1,048,576
  float* cnorm = ws + 12255232;     // 2,048
  float* pminb = ws + 12257280;     // 29,184
  int*   pidxb = (int*)(ws + 12286464); // 29,184
  float* lpart = ws + 12315648;     // 3,648 -> ends 12,319,296

  float* zq      = (float*)d_out;
  float* outLoss = zq + (size_t)B_ * L_ * D_;
  float* outIdx  = outLoss + 1;

  // weight re-layouts (tiny; dedicated region never touched by convs)
  wtrans_k<<<(1050 * 64 + 255) / 256, 256, 0, stream>>>(w1, wT1, 1050, 64);
  wtrans_k<<<( 192 * 128 + 255) / 256, 256, 0, stream>>>(w2, wT2, 192, 128);
  wtrans_k<<<( 384 * 256 + 255) / 256, 256, 0, stream>>>(w3, wT3, 384, 256);
  wtrans_k<<<( 768 * 512 + 255) / 256, 256, 0, stream>>>(w4, wT4, 768, 512);
  wtrans_k<<<(1024 * 512 + 255) / 256, 256, 0, stream>>>(w5, wT5, 1024, 512);
  wtrans_k<<<(1024 * 512 + 255) / 256, 256, 0, stream>>>(w6, wT6, 1024, 512);

  // conv stack in two batch-halves of 32 (keeps ping-pong buffers small)
  for (int h = 0; h < 2; ++h) {
    const float* xh = x + (size_t)h * HB_ * 105 * 5500;
    float* c6h = c6 + (size_t)h * HB_ * D_ * L_;
    conv1d_k<105,10,3, 64,35><<<dim3(29,1,HB_),256,0,stream>>>(xh,   wT1,b1, bufA, 5500,1831);
    conv1d_k< 64, 3,2,128,64><<<dim3(15,2,HB_),256,0,stream>>>(bufA, wT2,b2, bufB, 1831, 915);
    conv1d_k<128, 3,2,256,64><<<dim3( 8,4,HB_),256,0,stream>>>(bufB, wT3,b3, bufA,  915, 457);
    conv1d_k<256, 3,2,512,64><<<dim3( 4,8,HB_),256,0,stream>>>(bufA, wT4,b4, bufB,  457, 228);
    conv1d_k<512, 2,2,512,64><<<dim3( 2,8,HB_),256,0,stream>>>(bufB, wT5,b5, bufA,  228, 114);
    conv1d_k<512, 2,2,512,64><<<dim3( 1,8,HB_),256,0,stream>>>(bufA, wT6,b6, c6h,  114,  57);
  }

  transpose_k<<<dim3(16, B_), 256, 0, stream>>>(c6, xT);
  qkv3_k<<<dim3(24, B_), 256, 0, stream>>>(xT, wq, wk, wv, qb, kb, vb);
  cbprep_k<<<NC_, 64, 0, stream>>>(cbook, cbT, cnorm);
  attn_k<<<B_ * H_, 256, 0, stream>>>(qb, kb, vb, cat);
  outproj_k<<<dim3(4, B_), 256, 0, stream>>>(cat, wo, bo, yattn);

  vqpart_k<<<dim3(8, B_), 256, 0, stream>>>(yattn, cbT, cnorm, pminb, pidxb);
  vqfin_k<<<B_ * L_, 64, 0, stream>>>(yattn, cbook, pminb, pidxb, zq, outIdx, lpart);
  loss_k<<<1, 256, 0, stream>>>(lpart, outLoss);
}

// Round 4
// 1769.612 us; speedup vs baseline: 1.2356x; 1.1899x over previous
//
#include <hip/hip_runtime.h>
#include <hip/hip_bf16.h>
#include <math.h>

#define B_ 64
#define HB_ 32
#define L_ 57
#define D_ 512
#define H_ 8
#define DK_ 64
#define NC_ 2048

// ---------------- weight transpose: w[cout][cin][k] -> wT[cin*K + k][cout]
__global__ __launch_bounds__(256) void wtrans_k(const float* __restrict__ w,
                                                float* __restrict__ wT,
                                                int CINK, int COUT)
{
  int idx = blockIdx.x * 256 + threadIdx.x;
  if (idx >= CINK * COUT) return;
  int r = idx / COUT, c = idx - r * COUT;
  wT[idx] = w[(size_t)c * CINK + r];
}

// ---------------- conv1d over a 32-batch half (unchanged from round 3)
template<int CIN, int K, int S, int COUT, int CC>
__global__ __launch_bounds__(256) void conv1d_k(
    const float* __restrict__ x, const float* __restrict__ wT,
    const float* __restrict__ bias, float* __restrict__ y,
    int Tin, int Tout)
{
  constexpr int TT = 64;
  constexpr int SPAN = S * TT + K - S;   // <= 256 for all configs
  __shared__ float xs[CC * SPAN];
  const int b   = blockIdx.z;
  const int cbk = blockIdx.y;
  const int t0  = blockIdx.x * TT;
  const int tid = threadIdx.x;
  const int lane_t = tid & 63;
  const int g = tid >> 6;
  const int coutBase = __builtin_amdgcn_readfirstlane(cbk * 64 + g * 16);
  const int t = t0 + lane_t;
  float acc[16];
#pragma unroll
  for (int j = 0; j < 16; ++j) acc[j] = 0.f;
  const float* xb = x + (size_t)b * CIN * Tin;
  const int col0 = t0 * S;

  for (int c0 = 0; c0 < CIN; c0 += CC) {
    __syncthreads();
    for (int e = tid; e < CC * SPAN; e += 256) {
      int cc = e / SPAN, col = e - cc * SPAN;
      int ti = col0 + col;
      xs[e] = (ti < Tin) ? xb[(size_t)(c0 + cc) * Tin + ti] : 0.f;
    }
    __syncthreads();

    const float* wchunk = wT + ((size_t)c0 * K) * COUT + coutBase;
    for (int cc = 0; cc < CC; ++cc) {
#pragma unroll
      for (int kk = 0; kk < K; ++kk) {
        const float* wrow = wchunk + (size_t)(cc * K + kk) * COUT;
        float wv[16];
#pragma unroll
        for (int j = 0; j < 16; ++j) wv[j] = wrow[j];
        float xv = xs[cc * SPAN + lane_t * S + kk];
#pragma unroll
        for (int j = 0; j < 16; ++j) acc[j] += xv * wv[j];
      }
    }
  }
  if (t < Tout) {
#pragma unroll
    for (int j = 0; j < 16; ++j) {
      int co = coutBase + j;
      y[((size_t)b * COUT + co) * Tout + t] = acc[j] + bias[co];
    }
  }
}

// ---------------- transpose c6 [B,512,57] -> xT [B,57,512]
__global__ __launch_bounds__(256) void transpose_k(const float* __restrict__ c6,
                                                   float* __restrict__ xT)
{
  const int b = blockIdx.y, dt = blockIdx.x;  // 16 tiles of 32 d
  __shared__ float tile[32 * 58];
  const int tid = threadIdx.x;
  const int d0 = dt * 32;
  for (int e = tid; e < 32 * L_; e += 256) {
    int dd = e / L_, l = e - dd * L_;
    tile[dd * 58 + l] = c6[((size_t)b * D_ + d0 + dd) * L_ + l];
  }
  __syncthreads();
  for (int e = tid; e < L_ * 32; e += 256) {
    int l = e >> 5, dd = e & 31;
    xT[((size_t)b * L_ + l) * D_ + d0 + dd] = tile[dd * 58 + l];
  }
}

// ---------------- inverse transpose yattn [B,57,512] -> yT [B,512,57]
__global__ __launch_bounds__(256) void itranspose_k(const float* __restrict__ y,
                                                    float* __restrict__ yT)
{
  const int b = blockIdx.y, dt = blockIdx.x;  // 16 tiles of 32 d
  __shared__ float tile[32 * 58];
  const int tid = threadIdx.x;
  const int d0 = dt * 32;
  for (int e = tid; e < L_ * 32; e += 256) {
    int l = e >> 5, dd = e & 31;
    tile[dd * 58 + l] = y[((size_t)b * L_ + l) * D_ + d0 + dd];
  }
  __syncthreads();
  for (int e = tid; e < 32 * L_; e += 256) {
    int dd = e / L_, l = e - dd * L_;
    yT[((size_t)b * D_ + d0 + dd) * L_ + l] = tile[dd * 58 + l];
  }
}

// ---------------- fused QKV projection: out[b,h,l,kd] for q,k,v
__global__ __launch_bounds__(256) void qkv3_k(
    const float* __restrict__ xT, const float* __restrict__ wq,
    const float* __restrict__ wk, const float* __restrict__ wv,
    float* __restrict__ q, float* __restrict__ k, float* __restrict__ v)
{
  const int b = blockIdx.y;
  const int ot = blockIdx.x >> 2;
  const int lt = blockIdx.x & 3;
  const int l0 = lt * 16;
  __shared__ __align__(16) float cs[16 * D_];
  const int tid = threadIdx.x;
  for (int e = tid; e < 16 * D_; e += 256) {
    int l = l0 + (e >> 9);
    cs[e] = (l < L_) ? xT[((size_t)b * L_ + l) * D_ + (e & 511)] : 0.f;
  }
  __syncthreads();
  const int o3 = ot * 256 + tid;
  const int set = o3 >> 9;            // uniform per block
  const int oo = o3 & 511;
  const int h = oo >> 6, kd = oo & 63;
  const float* W = (set == 0 ? wq : (set == 1 ? wk : wv));
  const float* wp = W + (size_t)h * D_ * DK_ + kd;
  float acc[16];
#pragma unroll
  for (int j = 0; j < 16; ++j) acc[j] = 0.f;
  for (int d = 0; d < D_; d += 4) {
    float w0 = wp[(size_t)d * DK_];
    float w1 = wp[(size_t)(d + 1) * DK_];
    float w2 = wp[(size_t)(d + 2) * DK_];
    float w3 = wp[(size_t)(d + 3) * DK_];
#pragma unroll
    for (int j = 0; j < 16; ++j) {
      const float4 c4 = *reinterpret_cast<const float4*>(&cs[j * D_ + d]);
      acc[j] += c4.x * w0 + c4.y * w1 + c4.z * w2 + c4.w * w3;
    }
  }
  float* OUT = (set == 0 ? q : (set == 1 ? k : v));
#pragma unroll
  for (int j = 0; j < 16; ++j) {
    int l = l0 + j;
    if (l < L_) OUT[(((size_t)b * H_ + h) * L_ + l) * DK_ + kd] = acc[j];
  }
}

// ---------------- attention per (b,h); writes concat layout cat[b][l][h*64+kd]
__global__ __launch_bounds__(256) void attn_k(
    const float* __restrict__ q, const float* __restrict__ k, const float* __restrict__ v,
    float* __restrict__ cat)
{
  const int bh = blockIdx.x;
  const int b = bh >> 3, h = bh & 7;
  __shared__ float qs[L_ * DK_];
  __shared__ float ks[L_ * 65];      // padded: kills 32-way bank conflict
  __shared__ float vs[L_ * DK_];
  __shared__ float ps[L_ * DK_];
  const int tid = threadIdx.x;
  const float* qb = q + (size_t)bh * L_ * DK_;
  const float* kb = k + (size_t)bh * L_ * DK_;
  const float* vb = v + (size_t)bh * L_ * DK_;
  for (int e = tid; e < L_ * DK_; e += 256) {
    qs[e] = qb[e];
    vs[e] = vb[e];
    int m = e >> 6, d = e & 63;
    ks[m * 65 + d] = kb[e];
  }
  __syncthreads();
  for (int e = tid; e < L_ * L_; e += 256) {
    int l = e / L_, m = e - (e / L_) * L_;
    float s = 0.f;
#pragma unroll
    for (int d = 0; d < DK_; ++d) s += qs[l * DK_ + d] * ks[m * 65 + d];
    ps[l * DK_ + m] = s * 0.125f;
  }
  __syncthreads();
  if (tid < L_) {
    float mx = -1e30f;
    for (int m = 0; m < L_; ++m) mx = fmaxf(mx, ps[tid * DK_ + m]);
    float sum = 0.f;
    for (int m = 0; m < L_; ++m) { float e2 = __expf(ps[tid * DK_ + m] - mx); ps[tid * DK_ + m] = e2; sum += e2; }
    float inv = 1.f / sum;
    for (int m = 0; m < L_; ++m) ps[tid * DK_ + m] *= inv;
  }
  __syncthreads();
  for (int e = tid; e < L_ * DK_; e += 256) {
    int l = e >> 6, kd = e & 63;
    float s = 0.f;
    for (int m = 0; m < L_; ++m) s += ps[l * DK_ + m] * vs[m * DK_ + kd];
    cat[((size_t)b * L_ + l) * D_ + h * DK_ + kd] = s;
  }
}

// ---------------- output projection: y[b,l,o] = cat[b,l,:] @ wo + bo
__global__ __launch_bounds__(256) void outproj_k(
    const float* __restrict__ cat, const float* __restrict__ wo,
    const float* __restrict__ bo, float* __restrict__ y)
{
  const int b = blockIdx.y, lt = blockIdx.x;
  const int l0 = lt * 16;
  __shared__ __align__(16) float cs[16 * D_];
  const int tid = threadIdx.x;
  for (int e = tid; e < 16 * D_; e += 256) {
    int l = l0 + (e >> 9);
    cs[e] = (l < L_) ? cat[((size_t)b * L_ + l) * D_ + (e & 511)] : 0.f;
  }
  __syncthreads();
  float acc0[16], acc1[16];
#pragma unroll
  for (int j = 0; j < 16; ++j) { acc0[j] = 0.f; acc1[j] = 0.f; }
  for (int d = 0; d < D_; d += 4) {
    float w00 = wo[(size_t)d * D_ + tid];
    float w01 = wo[(size_t)(d + 1) * D_ + tid];
    float w02 = wo[(size_t)(d + 2) * D_ + tid];
    float w03 = wo[(size_t)(d + 3) * D_ + tid];
    float w10 = wo[(size_t)d * D_ + tid + 256];
    float w11 = wo[(size_t)(d + 1) * D_ + tid + 256];
    float w12 = wo[(size_t)(d + 2) * D_ + tid + 256];
    float w13 = wo[(size_t)(d + 3) * D_ + tid + 256];
#pragma unroll
    for (int j = 0; j < 16; ++j) {
      const float4 c4 = *reinterpret_cast<const float4*>(&cs[j * D_ + d]);
      acc0[j] += c4.x * w00 + c4.y * w01 + c4.z * w02 + c4.w * w03;
      acc1[j] += c4.x * w10 + c4.y * w11 + c4.z * w12 + c4.w * w13;
    }
  }
#pragma unroll
  for (int j = 0; j < 16; ++j) {
    int l = l0 + j;
    if (l < L_) {
      y[((size_t)b * L_ + l) * D_ + tid] = acc0[j] + bo[tid];
      y[((size_t)b * L_ + l) * D_ + tid + 256] = acc1[j] + bo[tid + 256];
    }
  }
}

// ---------------- codebook prep: transpose to [d][n] + norms
__global__ __launch_bounds__(64) void cbprep_k(const float* __restrict__ cb,
                                               float* __restrict__ cbT,
                                               float* __restrict__ cnorm)
{
  const int n = blockIdx.x, t = threadIdx.x;
  float s = 0.f;
  for (int d = t; d < D_; d += 64) {
    float vv = cb[(size_t)n * D_ + d];
    cbT[(size_t)d * NC_ + n] = vv;
    s += vv * vv;
  }
#pragma unroll
  for (int off = 32; off >= 1; off >>= 1) s += __shfl_xor(s, off);
  if (t == 0) cnorm[n] = s;
}

// ---------------- VQ distance GEMM + partial argmin.
// Block = (b, 256-code tile); 4 waves; wave tile 64l x 64n; lane 8x8 microtile.
// Per d: 4 ds_read_b128 feed 64 FMAs (16 FMA-instr : 1 ds-instr).
__global__ __launch_bounds__(256, 2) void vqgemm_k(
    const float* __restrict__ yT, const float* __restrict__ cbT,
    const float* __restrict__ cnorm, float* __restrict__ pmin, int* __restrict__ pidx)
{
  const int b = blockIdx.y, nt = blockIdx.x;
  const int tid = threadIdx.x;
  const int w = tid >> 6, lane = tid & 63;
  const int lrow = lane >> 3, ncol = lane & 7;
  __shared__ __align__(16) float As[32 * 68];    // [d][l], pitch 68 (16B-aligned rows)
  __shared__ __align__(16) float Bs[32 * 256];   // [d][n]
  __shared__ float redv[4][64];
  __shared__ int   redi[4][64];
  float acc[8][8];
#pragma unroll
  for (int li = 0; li < 8; ++li)
#pragma unroll
    for (int nj = 0; nj < 8; ++nj) acc[li][nj] = 0.f;

  const float* yTb = yT + (size_t)b * D_ * L_;
  const int n0 = nt * 256;
  const int nbase = n0 + w * 64 + ncol * 8;

  for (int d0 = 0; d0 < D_; d0 += 32) {
    __syncthreads();
    // stage A: 32d x 64l (zero-pad l >= 57); coalesced from yT
#pragma unroll
    for (int i = 0; i < 8; ++i) {
      int e = tid + i * 256;
      int dd = e >> 6, l = e & 63;
      As[dd * 68 + l] = (l < L_) ? yTb[(size_t)(d0 + dd) * L_ + l] : 0.f;
    }
    // stage B: 32d x 256n; float4-coalesced from cbT
#pragma unroll
    for (int i = 0; i < 8; ++i) {
      int e = tid + i * 256;
      int dd = e >> 6, n4 = (e & 63) * 4;
      *reinterpret_cast<float4*>(&Bs[dd * 256 + n4]) =
          *reinterpret_cast<const float4*>(&cbT[(size_t)(d0 + dd) * NC_ + n0 + n4]);
    }
    __syncthreads();
#pragma unroll 4
    for (int dd = 0; dd < 32; ++dd) {
      float a8[8], b8[8];
      *reinterpret_cast<float4*>(&a8[0]) = *reinterpret_cast<const float4*>(&As[dd * 68 + lrow * 8]);
      *reinterpret_cast<float4*>(&a8[4]) = *reinterpret_cast<const float4*>(&As[dd * 68 + lrow * 8 + 4]);
      *reinterpret_cast<float4*>(&b8[0]) = *reinterpret_cast<const float4*>(&Bs[dd * 256 + w * 64 + ncol * 8]);
      *reinterpret_cast<float4*>(&b8[4]) = *reinterpret_cast<const float4*>(&Bs[dd * 256 + w * 64 + ncol * 8 + 4]);
#pragma unroll
      for (int li = 0; li < 8; ++li)
#pragma unroll
        for (int nj = 0; nj < 8; ++nj)
          acc[li][nj] += a8[li] * b8[nj];
    }
  }

  // epilogue: val = |c|^2 - 2*dot; argmin with first-index tie-break
  float cn[8];
  *reinterpret_cast<float4*>(&cn[0]) = *reinterpret_cast<const float4*>(&cnorm[nbase]);
  *reinterpret_cast<float4*>(&cn[4]) = *reinterpret_cast<const float4*>(&cnorm[nbase + 4]);
#pragma unroll
  for (int li = 0; li < 8; ++li) {
    float vb = cn[0] - 2.f * acc[li][0];
    int ib = nbase;
#pragma unroll
    for (int nj = 1; nj < 8; ++nj) {
      float v = cn[nj] - 2.f * acc[li][nj];
      if (v < vb) { vb = v; ib = nbase + nj; }   // ascending n: strict < keeps first
    }
#pragma unroll
    for (int off = 1; off <= 4; off <<= 1) {
      float vo = __shfl_xor(vb, off);
      int io = __shfl_xor(ib, off);
      if (vo < vb || (vo == vb && io < ib)) { vb = vo; ib = io; }
    }
    if (ncol == 0) { redv[w][lrow * 8 + li] = vb; redi[w][lrow * 8 + li] = ib; }
  }
  __syncthreads();
  if (tid < L_) {
    float vb = redv[0][tid]; int ib = redi[0][tid];
#pragma unroll
    for (int w2 = 1; w2 < 4; ++w2) {
      float vo = redv[w2][tid]; int io = redi[w2][tid];
      if (vo < vb || (vo == vb && io < ib)) { vb = vo; ib = io; }
    }
    pmin[((size_t)b * L_ + tid) * 8 + nt] = vb;
    pidx[((size_t)b * L_ + tid) * 8 + nt] = ib;
  }
}

// ---------------- VQ final: pick global argmin, emit z_q + index + loss partial
__global__ __launch_bounds__(64) void vqfin_k(
    const float* __restrict__ y, const float* __restrict__ cbook,
    const float* __restrict__ pmin, const int* __restrict__ pidx,
    float* __restrict__ zq, float* __restrict__ oidx, float* __restrict__ lpart)
{
  const int bl = blockIdx.x;
  const int tid = threadIdx.x;
  __shared__ int sidx;
  if (tid == 0) {
    float vb = pmin[(size_t)bl * 8];
    int ib = pidx[(size_t)bl * 8];
    for (int ntv = 1; ntv < 8; ++ntv) {
      float vo = pmin[(size_t)bl * 8 + ntv];
      int io = pidx[(size_t)bl * 8 + ntv];
      if (vo < vb || (vo == vb && io < ib)) { vb = vo; ib = io; }
    }
    sidx = ib;
  }
  __syncthreads();
  const int idx = sidx;
  const float* crow = cbook + (size_t)idx * D_;
  const float* yrow = y + (size_t)bl * D_;
  float s = 0.f;
  for (int d = tid; d < D_; d += 64) {
    float c = crow[d];
    float df = c - yrow[d];
    zq[(size_t)bl * D_ + d] = c;
    s += df * df;
  }
#pragma unroll
  for (int off = 32; off >= 1; off >>= 1) s += __shfl_xor(s, off);
  if (tid == 0) { lpart[bl] = s; oidx[bl] = (float)idx; }
}

// ---------------- loss reduce (deterministic fixed-order)
__global__ __launch_bounds__(256) void loss_k(const float* __restrict__ lpart,
                                              float* __restrict__ outLoss)
{
  const int tid = threadIdx.x;
  float s = 0.f;
  for (int i = tid; i < B_ * L_; i += 256) s += lpart[i];
  __shared__ float red[256];
  red[tid] = s;
  __syncthreads();
  for (int off = 128; off >= 1; off >>= 1) {
    if (tid < off) red[tid] += red[tid + off];
    __syncthreads();
  }
  if (tid == 0) outLoss[0] = red[0] * ((1.f + 0.2f) / (float)((size_t)B_ * L_ * D_));
}

extern "C" void kernel_launch(void* const* d_in, const int* in_sizes, int n_in,
                              void* d_out, int out_size, void* d_ws, size_t ws_size,
                              hipStream_t stream)
{
  const float* x  = (const float*)d_in[0];
  const float* w1 = (const float*)d_in[1];  const float* b1 = (const float*)d_in[2];
  const float* w2 = (const float*)d_in[3];  const float* b2 = (const float*)d_in[4];
  const float* w3 = (const float*)d_in[5];  const float* b3 = (const float*)d_in[6];
  const float* w4 = (const float*)d_in[7];  const float* b4 = (const float*)d_in[8];
  const float* w5 = (const float*)d_in[9];  const float* b5 = (const float*)d_in[10];
  const float* w6 = (const float*)d_in[11]; const float* b6 = (const float*)d_in[12];
  const float* wq = (const float*)d_in[13];
  const float* wk = (const float*)d_in[14];
  const float* wv = (const float*)d_in[15];
  const float* wo = (const float*)d_in[16];
  const float* bo = (const float*)d_in[17];
  const float* cbook = (const float*)d_in[18];

  float* ws = (float*)d_ws;
  // ---- Workspace layout (floats), peak ~12.32M (~49.3MB) ----
  float* wT1 = ws;                  // 67,200
  float* wT2 = ws + 67200;          // 24,576
  float* wT3 = ws + 91776;          // 98,304
  float* wT4 = ws + 190080;         // 393,216
  float* wT5 = ws + 583296;         // 524,288
  float* wT6 = ws + 1107584;        // 524,288 -> ends 1,631,872
  float* bufA = ws + 1632000;       // 3,750,016
  float* bufB = ws + 5382016;       // 3,750,016
  float* c6   = ws + 9132032;       // 1,867,776
  // post-conv reuse (stream-serialized):
  float* qb    = ws;                // 1,867,776 (wT dead after convs)
  float* kb    = ws + 1867776;
  float* vb    = ws + 3735552;
  float* xT    = ws + 5603328;
  float* cat   = ws + 7471104;
  float* yattn = ws + 9338880;      // (c6 dead)
  float* cbT   = ws + 11206656;     // 1,048,576
  float* cnorm = ws + 12255232;     // 2,048
  float* pminb = ws + 12257280;     // 29,184
  int*   pidxb = (int*)(ws + 12286464); // 29,184
  float* lpart = ws + 12315648;     // 3,648
  float* yT    = ws;                // 1,867,776 (qb dead after attn_k)

  float* zq      = (float*)d_out;
  float* outLoss = zq + (size_t)B_ * L_ * D_;
  float* outIdx  = outLoss + 1;

  // weight re-layouts
  wtrans_k<<<(1050 * 64 + 255) / 256, 256, 0, stream>>>(w1, wT1, 1050, 64);
  wtrans_k<<<( 192 * 128 + 255) / 256, 256, 0, stream>>>(w2, wT2, 192, 128);
  wtrans_k<<<( 384 * 256 + 255) / 256, 256, 0, stream>>>(w3, wT3, 384, 256);
  wtrans_k<<<( 768 * 512 + 255) / 256, 256, 0, stream>>>(w4, wT4, 768, 512);
  wtrans_k<<<(1024 * 512 + 255) / 256, 256, 0, stream>>>(w5, wT5, 1024, 512);
  wtrans_k<<<(1024 * 512 + 255) / 256, 256, 0, stream>>>(w6, wT6, 1024, 512);

  // conv stack in two batch-halves of 32
  for (int h = 0; h < 2; ++h) {
    const float* xh = x + (size_t)h * HB_ * 105 * 5500;
    float* c6h = c6 + (size_t)h * HB_ * D_ * L_;
    conv1d_k<105,10,3, 64,35><<<dim3(29,1,HB_),256,0,stream>>>(xh,   wT1,b1, bufA, 5500,1831);
    conv1d_k< 64, 3,2,128,64><<<dim3(15,2,HB_),256,0,stream>>>(bufA, wT2,b2, bufB, 1831, 915);
    conv1d_k<128, 3,2,256,64><<<dim3( 8,4,HB_),256,0,stream>>>(bufB, wT3,b3, bufA,  915, 457);
    conv1d_k<256, 3,2,512,64><<<dim3( 4,8,HB_),256,0,stream>>>(bufA, wT4,b4, bufB,  457, 228);
    conv1d_k<512, 2,2,512,64><<<dim3( 2,8,HB_),256,0,stream>>>(bufB, wT5,b5, bufA,  228, 114);
    conv1d_k<512, 2,2,512,64><<<dim3( 1,8,HB_),256,0,stream>>>(bufA, wT6,b6, c6h,  114,  57);
  }

  transpose_k<<<dim3(16, B_), 256, 0, stream>>>(c6, xT);
  qkv3_k<<<dim3(24, B_), 256, 0, stream>>>(xT, wq, wk, wv, qb, kb, vb);
  cbprep_k<<<NC_, 64, 0, stream>>>(cbook, cbT, cnorm);
  attn_k<<<B_ * H_, 256, 0, stream>>>(qb, kb, vb, cat);
  outproj_k<<<dim3(4, B_), 256, 0, stream>>>(cat, wo, bo, yattn);

  itranspose_k<<<dim3(16, B_), 256, 0, stream>>>(yattn, yT);
  vqgemm_k<<<dim3(8, B_), 256, 0, stream>>>(yT, cbT, cnorm, pminb, pidxb);
  vqfin_k<<<B_ * L_, 64, 0, stream>>>(yattn, cbook, pminb, pidxb, zq, outIdx, lpart);
  loss_k<<<1, 256, 0, stream>>>(lpart, outLoss);
}